// Round 1
// baseline (1453.819 us; speedup 1.0000x reference)
//
#include <hip/hip_runtime.h>
#include <hip/hip_bf16.h>
#include <math.h>

// Shapes
#define N_TRAIN 4096
#define N_FEAT  64
#define N_HID   256
#define ENC     256
#define N_ANTES 2048
#define ATT_H   256
#define MAX_LEN 16

__device__ __forceinline__ float fsig(float x)  { return 1.f / (1.f + __expf(-x)); }
__device__ __forceinline__ float ftanh(float x) { return 2.f / (1.f + __expf(-2.f * x)) - 1.f; }

// ---------------------------------------------------------------------------
// Generic tiled GEMM: C[m,n] = act(bias[n] + sum_k A[m,k] * B[n,k])
// A: (M,K) row-major lda; B: (N,K) row-major ldb; C: (M,N) ldc.
// Tiles 64x64x16, 256 threads, 4x4 micro-tile. M,N % 64 == 0, K % 16 == 0.
// ---------------------------------------------------------------------------
template <bool RELU>
__global__ __launch_bounds__(256) void gemm_abT(
    const float* __restrict__ A, const float* __restrict__ B,
    const float* __restrict__ bias, float* __restrict__ C,
    int M, int N, int K, int lda, int ldb, int ldc)
{
    __shared__ float As[16][65];
    __shared__ float Bs[16][65];
    const int tid = threadIdx.x;
    const int m0 = blockIdx.x * 64, n0 = blockIdx.y * 64;
    const int tx = tid & 15, ty = tid >> 4;
    const int kl = tid & 15, rl = tid >> 4;   // load indices: 16 k x 16 rows/pass
    float acc[4][4] = {};

    for (int k0 = 0; k0 < K; k0 += 16) {
        #pragma unroll
        for (int pp = 0; pp < 4; ++pp) {
            int r = rl + pp * 16;
            As[kl][r] = A[(size_t)(m0 + r) * lda + k0 + kl];
            Bs[kl][r] = B[(size_t)(n0 + r) * ldb + k0 + kl];
        }
        __syncthreads();
        #pragma unroll
        for (int k = 0; k < 16; ++k) {
            float a[4], b[4];
            #pragma unroll
            for (int i = 0; i < 4; ++i) a[i] = As[k][ty * 4 + i];
            #pragma unroll
            for (int i = 0; i < 4; ++i) b[i] = Bs[k][tx * 4 + i];
            #pragma unroll
            for (int i = 0; i < 4; ++i)
                #pragma unroll
                for (int j = 0; j < 4; ++j)
                    acc[i][j] = fmaf(a[i], b[j], acc[i][j]);
        }
        __syncthreads();
    }
    #pragma unroll
    for (int i = 0; i < 4; ++i) {
        int m = m0 + ty * 4 + i;
        #pragma unroll
        for (int j = 0; j < 4; ++j) {
            int n = n0 + tx * 4 + j;
            float v = acc[i][j] + bias[n];
            if (RELU) v = fmaxf(v, 0.f);
            C[(size_t)m * ldc + n] = v;
        }
    }
}

// ---------------------------------------------------------------------------
// C[m,n] = sum_k A[m,k] * B[k,n].  A: (M,K) lda; B: (K,N) ldb; C: (M,N) ldc.
// Used for preT = Wa @ S  (M=256 j, K=4096 n, N=2048 p).
// ---------------------------------------------------------------------------
__global__ __launch_bounds__(256) void gemm_ab(
    const float* __restrict__ A, const float* __restrict__ B,
    float* __restrict__ C, int M, int N, int K, int lda, int ldb, int ldc)
{
    __shared__ float As[16][65];
    __shared__ float Bs[16][64];
    const int tid = threadIdx.x;
    const int m0 = blockIdx.x * 64, n0 = blockIdx.y * 64;
    const int tx = tid & 15, ty = tid >> 4;
    const int kl = tid & 15, rl = tid >> 4;   // A loads
    const int kb = tid >> 6, nb = tid & 63;   // B loads: 4 k-rows per pass
    float acc[4][4] = {};

    for (int k0 = 0; k0 < K; k0 += 16) {
        #pragma unroll
        for (int pp = 0; pp < 4; ++pp) {
            As[kl][rl + pp * 16] = A[(size_t)(m0 + rl + pp * 16) * lda + k0 + kl];
            Bs[kb + pp * 4][nb]  = B[(size_t)(k0 + kb + pp * 4) * ldb + n0 + nb];
        }
        __syncthreads();
        #pragma unroll
        for (int k = 0; k < 16; ++k) {
            float a[4], b[4];
            #pragma unroll
            for (int i = 0; i < 4; ++i) a[i] = As[k][ty * 4 + i];
            #pragma unroll
            for (int i = 0; i < 4; ++i) b[i] = Bs[k][tx * 4 + i];
            #pragma unroll
            for (int i = 0; i < 4; ++i)
                #pragma unroll
                for (int j = 0; j < 4; ++j)
                    acc[i][j] = fmaf(a[i], b[j], acc[i][j]);
        }
        __syncthreads();
    }
    #pragma unroll
    for (int i = 0; i < 4; ++i)
        #pragma unroll
        for (int j = 0; j < 4; ++j)
            C[(size_t)(m0 + ty * 4 + i) * ldc + n0 + tx * 4 + j] = acc[i][j];
}

// ---------------------------------------------------------------------------
// rowsum[j] = sum_k w_ih[j, k]   (one block per j)
// ---------------------------------------------------------------------------
__global__ __launch_bounds__(256) void k_rowsum(const float* __restrict__ w_ih,
                                                float* __restrict__ rowsum)
{
    __shared__ float red[256];
    const int j = blockIdx.x, tid = threadIdx.x;
    float s = 0.f;
    for (int i = tid; i < N_ANTES; i += 256) s += w_ih[(size_t)j * N_ANTES + i];
    red[tid] = s; __syncthreads();
    for (int off = 128; off > 0; off >>= 1) {
        if (tid < off) red[tid] += red[tid + off];
        __syncthreads();
    }
    if (tid == 0) rowsum[j] = red[0];
}

// ---------------------------------------------------------------------------
// w_pack[k*1024 + jj*4 + g] = w_hh[(g*256+jj)*256 + k]
// ---------------------------------------------------------------------------
__global__ __launch_bounds__(256) void k_pack(const float* __restrict__ w_hh,
                                              float* __restrict__ w_pack)
{
    int gid = blockIdx.x * 256 + threadIdx.x;  // 0..262143
    int row = gid >> 8;                        // g*256+jj
    int k   = gid & 255;
    int g   = row >> 8, jj = row & 255;
    w_pack[(size_t)k * 1024 + jj * 4 + g] = w_hh[gid];
}

// ---------------------------------------------------------------------------
// LSTM step: for ROWS rows per block, all 256 jj per thread:
//   z_g = a[r]*rowsum[g*256+jj] + dot(h[r,:], w_hh[g*256+jj,:]) + b_ih + b_hh
//   gate math, update c,h in place, atomically accumulate column sums of h.
// ---------------------------------------------------------------------------
#define ROWS 8
__global__ __launch_bounds__(256) void k_lstm(
    float* __restrict__ h, float* __restrict__ c,
    const float* __restrict__ w_pack, const float* __restrict__ rowsum,
    const float* __restrict__ b_ih, const float* __restrict__ b_hh,
    const float* __restrict__ S, const int* __restrict__ idx_buf, int t,
    float* __restrict__ e_accum_t)
{
    __shared__ float h_lds[256 * (ROWS + 1)];
    __shared__ float a_lds[ROWS];
    const int tid = threadIdx.x;
    const int n0 = blockIdx.x * ROWS;

    if (tid < ROWS) {
        float a = 1.0f;
        if (t > 0) a = S[(size_t)(n0 + tid) * N_ANTES + idx_buf[t - 1]];
        a_lds[tid] = a;
    }
    #pragma unroll
    for (int r = 0; r < ROWS; ++r)
        h_lds[tid * (ROWS + 1) + r] = h[(size_t)(n0 + r) * 256 + tid];
    __syncthreads();

    float rs[4], bs[4];
    #pragma unroll
    for (int g = 0; g < 4; ++g) {
        int j = g * 256 + tid;
        rs[g] = rowsum[j];
        bs[g] = b_ih[j] + b_hh[j];
    }
    float acc[4][ROWS];
    #pragma unroll
    for (int g = 0; g < 4; ++g)
        #pragma unroll
        for (int r = 0; r < ROWS; ++r)
            acc[g][r] = fmaf(a_lds[r], rs[g], bs[g]);

    const float4* __restrict__ wp4 = (const float4*)w_pack;
    #pragma unroll 2
    for (int k = 0; k < 256; ++k) {
        float4 w = wp4[(size_t)k * 256 + tid];
        float hk[ROWS];
        #pragma unroll
        for (int r = 0; r < ROWS; ++r) hk[r] = h_lds[k * (ROWS + 1) + r];
        #pragma unroll
        for (int r = 0; r < ROWS; ++r) {
            acc[0][r] = fmaf(w.x, hk[r], acc[0][r]);
            acc[1][r] = fmaf(w.y, hk[r], acc[1][r]);
            acc[2][r] = fmaf(w.z, hk[r], acc[2][r]);
            acc[3][r] = fmaf(w.w, hk[r], acc[3][r]);
        }
    }

    float esum = 0.f;
    #pragma unroll
    for (int r = 0; r < ROWS; ++r) {
        size_t off = (size_t)(n0 + r) * 256 + tid;
        float cold = c[off];
        float ig = fsig(acc[0][r]);
        float fg = fsig(acc[1][r]);
        float gg = ftanh(acc[2][r]);
        float og = fsig(acc[3][r]);
        float cn = fg * cold + ig * gg;
        float hn = og * ftanh(cn);
        c[off] = cn;
        h[off] = hn;
        esum += hn;
    }
    atomicAdd(&e_accum_t[tid], esum);
}

// ---------------------------------------------------------------------------
// Attention scores: u[j] = att_b1[j] + sum_k e_t[k]*Wb[j,k];
// scores[p] = att_b2 + sum_j relu(preT[j,p] + u[j]) * att_w2[j]
// ---------------------------------------------------------------------------
__global__ __launch_bounds__(256) void k_att1(
    const float* __restrict__ preT, const float* __restrict__ e_accum_t,
    const float* __restrict__ att_w1, const float* __restrict__ att_b1,
    const float* __restrict__ att_w2, const float* __restrict__ att_b2,
    float* __restrict__ scores)
{
    __shared__ float e_lds[256];
    __shared__ float u[256];
    __shared__ float w2[256];
    const int tid = threadIdx.x;
    e_lds[tid] = e_accum_t[tid] * (1.f / (float)N_TRAIN);
    w2[tid] = att_w2[tid];
    __syncthreads();

    const float* Wbrow = att_w1 + (size_t)tid * (N_TRAIN + ENC) + N_TRAIN;
    float acc = att_b1[tid];
    for (int k = 0; k < 256; ++k) acc = fmaf(e_lds[k], Wbrow[k], acc);
    u[tid] = acc;
    __syncthreads();

    const int p = blockIdx.x * 256 + tid;
    float sc = att_b2[0];
    for (int j = 0; j < 256; ++j) {
        float v = preT[(size_t)j * N_ANTES + p] + u[j];
        sc = fmaf(fmaxf(v, 0.f), w2[j], sc);
    }
    scores[p] = sc;
}

// ---------------------------------------------------------------------------
// log-softmax + argmax over 2048 scores (single block), write logp row + idx
// ---------------------------------------------------------------------------
__global__ __launch_bounds__(256) void k_att2(
    const float* __restrict__ scores, float* __restrict__ out_t,
    int* __restrict__ idx_t)
{
    __shared__ float smax[256];
    __shared__ int   sidx[256];
    __shared__ float ssum[256];
    const int tid = threadIdx.x;

    float lmax = -INFINITY; int lidx = 0;
    #pragma unroll
    for (int i = 0; i < 8; ++i) {
        int p = tid * 8 + i;
        float s = scores[p];
        if (s > lmax) { lmax = s; lidx = p; }
    }
    smax[tid] = lmax; sidx[tid] = lidx;
    __syncthreads();
    for (int off = 128; off > 0; off >>= 1) {
        if (tid < off) {
            float ov = smax[tid + off]; int oi = sidx[tid + off];
            if (ov > smax[tid] || (ov == smax[tid] && oi < sidx[tid])) {
                smax[tid] = ov; sidx[tid] = oi;
            }
        }
        __syncthreads();
    }
    const float gmax = smax[0];

    float lsum = 0.f;
    #pragma unroll
    for (int i = 0; i < 8; ++i) lsum += __expf(scores[tid * 8 + i] - gmax);
    ssum[tid] = lsum;
    __syncthreads();
    for (int off = 128; off > 0; off >>= 1) {
        if (tid < off) ssum[tid] += ssum[tid + off];
        __syncthreads();
    }
    const float lse = gmax + logf(ssum[0]);

    #pragma unroll
    for (int i = 0; i < 8; ++i) {
        int p = tid * 8 + i;
        out_t[p] = scores[p] - lse;
    }
    if (tid == 0) idx_t[0] = sidx[0];
}

// ---------------------------------------------------------------------------
extern "C" void kernel_launch(void* const* d_in, const int* in_sizes, int n_in,
                              void* d_out, int out_size, void* d_ws, size_t ws_size,
                              hipStream_t stream)
{
    (void)in_sizes; (void)n_in; (void)out_size; (void)ws_size;
    const float* context = (const float*)d_in[0];
    const float* S       = (const float*)d_in[1];
    const float* enc_w1  = (const float*)d_in[2];
    const float* enc_b1  = (const float*)d_in[3];
    const float* enc_w2  = (const float*)d_in[4];
    const float* enc_b2  = (const float*)d_in[5];
    const float* w_ih    = (const float*)d_in[6];
    const float* w_hh    = (const float*)d_in[7];
    const float* b_ih    = (const float*)d_in[8];
    const float* b_hh    = (const float*)d_in[9];
    const float* att_w1  = (const float*)d_in[10];
    const float* att_b1  = (const float*)d_in[11];
    const float* att_w2  = (const float*)d_in[12];
    const float* att_b2  = (const float*)d_in[13];
    float* out = (float*)d_out;
    float* ws  = (float*)d_ws;

    // ws layout (floats)
    float* h      = ws;                      // 4096*256 = 1048576
    float* c      = ws + 1048576;            // 1048576
    float* hid1   = ws + 2097152;            // 1048576 (aliased by preT after use)
    float* preT   = ws + 2097152;            // 2048*256 = 524288 (alias of hid1)
    float* wpk    = ws + 3145728;            // 256*1024 = 262144
    float* rowsum = ws + 3407872;            // 1024
    float* e_acc  = ws + 3408896;            // 16*256 = 4096
    float* scores = ws + 3412992;            // 2048
    int*   idxbuf = (int*)(ws + 3415040);    // 16 ints

    hipMemsetAsync(c, 0, (size_t)N_TRAIN * ENC * sizeof(float), stream);
    hipMemsetAsync(e_acc, 0, (size_t)MAX_LEN * ENC * sizeof(float), stream);

    k_rowsum<<<1024, 256, 0, stream>>>(w_ih, rowsum);
    k_pack<<<1024, 256, 0, stream>>>(w_hh, wpk);

    // hidden1 = relu(context @ enc_w1.T + enc_b1)
    dim3 g1(N_TRAIN / 64, N_HID / 64);
    gemm_abT<true><<<g1, 256, 0, stream>>>(context, enc_w1, enc_b1, hid1,
                                           N_TRAIN, N_HID, N_FEAT, N_FEAT, N_FEAT, N_HID);
    // h = phi = hidden1 @ enc_w2.T + enc_b2
    dim3 g2(N_TRAIN / 64, ENC / 64);
    gemm_abT<false><<<g2, 256, 0, stream>>>(hid1, enc_w2, enc_b2, h,
                                            N_TRAIN, ENC, N_HID, N_HID, N_HID, ENC);
    // NOTE: preT aliases hid1 — safe, gemm_ab runs after the read of hid1.
    // preT[j,p] = sum_n Wa[j,n] * S[n,p]
    dim3 g3(ATT_H / 64, N_ANTES / 64);
    gemm_ab<<<g3, 256, 0, stream>>>(att_w1, S, preT,
                                    ATT_H, N_ANTES, N_TRAIN,
                                    N_TRAIN + ENC, N_ANTES, N_ANTES);

    for (int t = 0; t < MAX_LEN; ++t) {
        k_lstm<<<N_TRAIN / ROWS, 256, 0, stream>>>(h, c, wpk, rowsum, b_ih, b_hh,
                                                   S, idxbuf, t, e_acc + t * 256);
        k_att1<<<N_ANTES / 256, 256, 0, stream>>>(preT, e_acc + t * 256, att_w1,
                                                  att_b1, att_w2, att_b2, scores);
        k_att2<<<1, 256, 0, stream>>>(scores, out + t * N_ANTES, idxbuf + t);
    }
}

// Round 2
// 1449.406 us; speedup vs baseline: 1.0030x; 1.0030x over previous
//
#include <hip/hip_runtime.h>
#include <hip/hip_bf16.h>
#include <math.h>

// Shapes
#define N_TRAIN 4096
#define N_FEAT  64
#define N_HID   256
#define ENC     256
#define N_ANTES 2048
#define ATT_H   256
#define MAX_LEN 16

__device__ __forceinline__ float fsig(float x)  { return 1.f / (1.f + __expf(-x)); }
__device__ __forceinline__ float ftanh(float x) { return 2.f / (1.f + __expf(-2.f * x)) - 1.f; }

// ---------------------------------------------------------------------------
// Generic tiled GEMM: C[m,n] = act(bias[n] + sum_k A[m,k] * B[n,k])
// A: (M,K) row-major lda; B: (N,K) row-major ldb; C: (M,N) ldc.
// Tiles 64x64x16, 256 threads, 4x4 micro-tile. M,N % 64 == 0, K % 16 == 0.
// ---------------------------------------------------------------------------
template <bool RELU>
__global__ __launch_bounds__(256) void gemm_abT(
    const float* __restrict__ A, const float* __restrict__ B,
    const float* __restrict__ bias, float* __restrict__ C,
    int M, int N, int K, int lda, int ldb, int ldc)
{
    __shared__ float As[16][65];
    __shared__ float Bs[16][65];
    const int tid = threadIdx.x;
    const int m0 = blockIdx.x * 64, n0 = blockIdx.y * 64;
    const int tx = tid & 15, ty = tid >> 4;
    const int kl = tid & 15, rl = tid >> 4;
    float acc[4][4] = {};

    for (int k0 = 0; k0 < K; k0 += 16) {
        #pragma unroll
        for (int pp = 0; pp < 4; ++pp) {
            int r = rl + pp * 16;
            As[kl][r] = A[(size_t)(m0 + r) * lda + k0 + kl];
            Bs[kl][r] = B[(size_t)(n0 + r) * ldb + k0 + kl];
        }
        __syncthreads();
        #pragma unroll
        for (int k = 0; k < 16; ++k) {
            float a[4], b[4];
            #pragma unroll
            for (int i = 0; i < 4; ++i) a[i] = As[k][ty * 4 + i];
            #pragma unroll
            for (int i = 0; i < 4; ++i) b[i] = Bs[k][tx * 4 + i];
            #pragma unroll
            for (int i = 0; i < 4; ++i)
                #pragma unroll
                for (int j = 0; j < 4; ++j)
                    acc[i][j] = fmaf(a[i], b[j], acc[i][j]);
        }
        __syncthreads();
    }
    #pragma unroll
    for (int i = 0; i < 4; ++i) {
        int m = m0 + ty * 4 + i;
        #pragma unroll
        for (int j = 0; j < 4; ++j) {
            int n = n0 + tx * 4 + j;
            float v = acc[i][j] + bias[n];
            if (RELU) v = fmaxf(v, 0.f);
            C[(size_t)m * ldc + n] = v;
        }
    }
}

// ---------------------------------------------------------------------------
// Split-K GEMM: C[m,n] += sum_k A[m,k] * B[k,n], k in this block's chunk.
// A: (M,K) lda; B: (K,N) ldb; C: (M,N) ldc, pre-zeroed; epilogue atomicAdd.
// Grid: (M/64, N/64, KSPLIT). Used for preT = Wa @ S.
// ---------------------------------------------------------------------------
#define KSPLIT 8
__global__ __launch_bounds__(256) void gemm_ab_splitk(
    const float* __restrict__ A, const float* __restrict__ B,
    float* __restrict__ C, int M, int N, int K, int lda, int ldb, int ldc)
{
    __shared__ float As[16][65];
    __shared__ float Bs[16][64];
    const int tid = threadIdx.x;
    const int m0 = blockIdx.x * 64, n0 = blockIdx.y * 64;
    const int kchunk = K / KSPLIT;
    const int kbeg = blockIdx.z * kchunk, kend = kbeg + kchunk;
    const int tx = tid & 15, ty = tid >> 4;
    const int kl = tid & 15, rl = tid >> 4;   // A loads
    const int kb = tid >> 6, nb = tid & 63;   // B loads
    float acc[4][4] = {};

    for (int k0 = kbeg; k0 < kend; k0 += 16) {
        #pragma unroll
        for (int pp = 0; pp < 4; ++pp) {
            As[kl][rl + pp * 16] = A[(size_t)(m0 + rl + pp * 16) * lda + k0 + kl];
            Bs[kb + pp * 4][nb]  = B[(size_t)(k0 + kb + pp * 4) * ldb + n0 + nb];
        }
        __syncthreads();
        #pragma unroll
        for (int k = 0; k < 16; ++k) {
            float a[4], b[4];
            #pragma unroll
            for (int i = 0; i < 4; ++i) a[i] = As[k][ty * 4 + i];
            #pragma unroll
            for (int i = 0; i < 4; ++i) b[i] = Bs[k][tx * 4 + i];
            #pragma unroll
            for (int i = 0; i < 4; ++i)
                #pragma unroll
                for (int j = 0; j < 4; ++j)
                    acc[i][j] = fmaf(a[i], b[j], acc[i][j]);
        }
        __syncthreads();
    }
    #pragma unroll
    for (int i = 0; i < 4; ++i)
        #pragma unroll
        for (int j = 0; j < 4; ++j)
            atomicAdd(&C[(size_t)(m0 + ty * 4 + i) * ldc + n0 + tx * 4 + j],
                      acc[i][j]);
}

// ---------------------------------------------------------------------------
// rowsum[j] = sum_k w_ih[j, k]
// ---------------------------------------------------------------------------
__global__ __launch_bounds__(256) void k_rowsum(const float* __restrict__ w_ih,
                                                float* __restrict__ rowsum)
{
    __shared__ float red[256];
    const int j = blockIdx.x, tid = threadIdx.x;
    float s = 0.f;
    for (int i = tid; i < N_ANTES; i += 256) s += w_ih[(size_t)j * N_ANTES + i];
    red[tid] = s; __syncthreads();
    for (int off = 128; off > 0; off >>= 1) {
        if (tid < off) red[tid] += red[tid + off];
        __syncthreads();
    }
    if (tid == 0) rowsum[j] = red[0];
}

// ---------------------------------------------------------------------------
// w_pack[k*1024 + jj*4 + g] = w_hh[(g*256+jj)*256 + k]
// ---------------------------------------------------------------------------
__global__ __launch_bounds__(256) void k_pack(const float* __restrict__ w_hh,
                                              float* __restrict__ w_pack)
{
    int gid = blockIdx.x * 256 + threadIdx.x;  // 0..262143
    int row = gid >> 8;                        // g*256+jj
    int k   = gid & 255;
    int g   = row >> 8, jj = row & 255;
    w_pack[(size_t)k * 1024 + jj * 4 + g] = w_hh[gid];
}

// ---------------------------------------------------------------------------
// LSTM step. ROWS rows per block, thread tid owns hidden unit jj=tid across
// all 4 gates. x@w_ih.T collapses to a[r]*rowsum[j] (x is rank-1).
// h tile staged transposed in LDS, stride 20 (16B-aligned rows, broadcast
// reads). w_pack streamed from L2 with one-deep manual prefetch (padded).
// ---------------------------------------------------------------------------
#define ROWS 16
#define HSTRIDE 20
__global__ __launch_bounds__(256) void k_lstm(
    float* __restrict__ h, float* __restrict__ c,
    const float* __restrict__ w_pack, const float* __restrict__ rowsum,
    const float* __restrict__ b_ih, const float* __restrict__ b_hh,
    const float* __restrict__ S, const int* __restrict__ idx_buf, int t,
    float* __restrict__ e_accum_t)
{
    __shared__ float h_lds[256 * HSTRIDE];
    __shared__ float a_lds[ROWS];
    const int tid = threadIdx.x;
    const int n0 = blockIdx.x * ROWS;

    if (tid < ROWS) {
        float a = 1.0f;
        if (t > 0) a = S[(size_t)(n0 + tid) * N_ANTES + idx_buf[t - 1]];
        a_lds[tid] = a;
    }
    #pragma unroll
    for (int r = 0; r < ROWS; ++r)
        h_lds[tid * HSTRIDE + r] = h[(size_t)(n0 + r) * 256 + tid];
    __syncthreads();

    float rs[4], bs[4];
    #pragma unroll
    for (int g = 0; g < 4; ++g) {
        int j = g * 256 + tid;
        rs[g] = rowsum[j];
        bs[g] = b_ih[j] + b_hh[j];
    }
    float acc[4][ROWS];
    #pragma unroll
    for (int g = 0; g < 4; ++g)
        #pragma unroll
        for (int r = 0; r < ROWS; ++r)
            acc[g][r] = fmaf(a_lds[r], rs[g], bs[g]);

    const float4* __restrict__ wp4 = (const float4*)w_pack;
    float4 wcur = wp4[tid];
    #pragma unroll 2
    for (int k = 0; k < 256; ++k) {
        float4 wnext = wp4[(size_t)(k + 1) * 256 + tid];  // row 256 = pad
        const float4* hrow = (const float4*)&h_lds[k * HSTRIDE];
        float4 h0 = hrow[0], h1 = hrow[1], h2 = hrow[2], h3 = hrow[3];
        float hk[ROWS] = {h0.x, h0.y, h0.z, h0.w, h1.x, h1.y, h1.z, h1.w,
                          h2.x, h2.y, h2.z, h2.w, h3.x, h3.y, h3.z, h3.w};
        #pragma unroll
        for (int r = 0; r < ROWS; ++r) {
            acc[0][r] = fmaf(wcur.x, hk[r], acc[0][r]);
            acc[1][r] = fmaf(wcur.y, hk[r], acc[1][r]);
            acc[2][r] = fmaf(wcur.z, hk[r], acc[2][r]);
            acc[3][r] = fmaf(wcur.w, hk[r], acc[3][r]);
        }
        wcur = wnext;
    }

    float esum = 0.f;
    #pragma unroll
    for (int r = 0; r < ROWS; ++r) {
        size_t off = (size_t)(n0 + r) * 256 + tid;
        float cold = c[off];
        float ig = fsig(acc[0][r]);
        float fg = fsig(acc[1][r]);
        float gg = ftanh(acc[2][r]);
        float og = fsig(acc[3][r]);
        float cn = fg * cold + ig * gg;
        float hn = og * ftanh(cn);
        c[off] = cn;
        h[off] = hn;
        esum += hn;
    }
    atomicAdd(&e_accum_t[tid], esum);
}

// ---------------------------------------------------------------------------
// Attention scores, 32 blocks x 256 threads; 4 threads per score column.
// u[j] = att_b1[j] + sum_k e_t[k]*Wb[j,k]  (redundant per block, tiny)
// scores[p] = att_b2 + sum_j relu(preT[j,p] + u[j]) * att_w2[j]
// ---------------------------------------------------------------------------
__global__ __launch_bounds__(256) void k_att1(
    const float* __restrict__ preT, const float* __restrict__ e_accum_t,
    const float* __restrict__ att_w1, const float* __restrict__ att_b1,
    const float* __restrict__ att_w2, const float* __restrict__ att_b2,
    float* __restrict__ scores)
{
    __shared__ float e_lds[256];
    __shared__ float u[256];
    __shared__ float w2s[256];
    __shared__ float red[256];
    const int tid = threadIdx.x;
    e_lds[tid] = e_accum_t[tid] * (1.f / (float)N_TRAIN);
    w2s[tid] = att_w2[tid];
    __syncthreads();

    const float* Wbrow = att_w1 + (size_t)tid * (N_TRAIN + ENC) + N_TRAIN;
    float uacc = att_b1[tid];
    for (int k = 0; k < 256; ++k) uacc = fmaf(e_lds[k], Wbrow[k], uacc);
    u[tid] = uacc;
    __syncthreads();

    const int pl = tid & 63, jq = tid >> 6;
    const int p = blockIdx.x * 64 + pl;
    float sc = 0.f;
    #pragma unroll 4
    for (int j = jq; j < 256; j += 4) {
        float v = preT[(size_t)j * N_ANTES + p] + u[j];
        sc = fmaf(fmaxf(v, 0.f), w2s[j], sc);
    }
    red[tid] = sc;
    __syncthreads();
    if (tid < 64)
        scores[blockIdx.x * 64 + tid] =
            red[tid] + red[tid + 64] + red[tid + 128] + red[tid + 192] + att_b2[0];
}

// ---------------------------------------------------------------------------
// log-softmax + argmax over 2048 scores (single block)
// ---------------------------------------------------------------------------
__global__ __launch_bounds__(256) void k_att2(
    const float* __restrict__ scores, float* __restrict__ out_t,
    int* __restrict__ idx_t)
{
    __shared__ float smax[256];
    __shared__ int   sidx[256];
    __shared__ float ssum[256];
    const int tid = threadIdx.x;

    float lmax = -INFINITY; int lidx = 0;
    #pragma unroll
    for (int i = 0; i < 8; ++i) {
        int p = tid * 8 + i;
        float s = scores[p];
        if (s > lmax) { lmax = s; lidx = p; }
    }
    smax[tid] = lmax; sidx[tid] = lidx;
    __syncthreads();
    for (int off = 128; off > 0; off >>= 1) {
        if (tid < off) {
            float ov = smax[tid + off]; int oi = sidx[tid + off];
            if (ov > smax[tid] || (ov == smax[tid] && oi < sidx[tid])) {
                smax[tid] = ov; sidx[tid] = oi;
            }
        }
        __syncthreads();
    }
    const float gmax = smax[0];

    float lsum = 0.f;
    #pragma unroll
    for (int i = 0; i < 8; ++i) lsum += __expf(scores[tid * 8 + i] - gmax);
    ssum[tid] = lsum;
    __syncthreads();
    for (int off = 128; off > 0; off >>= 1) {
        if (tid < off) ssum[tid] += ssum[tid + off];
        __syncthreads();
    }
    const float lse = gmax + logf(ssum[0]);

    #pragma unroll
    for (int i = 0; i < 8; ++i) {
        int p = tid * 8 + i;
        out_t[p] = scores[p] - lse;
    }
    if (tid == 0) idx_t[0] = sidx[0];
}

// ---------------------------------------------------------------------------
extern "C" void kernel_launch(void* const* d_in, const int* in_sizes, int n_in,
                              void* d_out, int out_size, void* d_ws, size_t ws_size,
                              hipStream_t stream)
{
    (void)in_sizes; (void)n_in; (void)out_size; (void)ws_size;
    const float* context = (const float*)d_in[0];
    const float* S       = (const float*)d_in[1];
    const float* enc_w1  = (const float*)d_in[2];
    const float* enc_b1  = (const float*)d_in[3];
    const float* enc_w2  = (const float*)d_in[4];
    const float* enc_b2  = (const float*)d_in[5];
    const float* w_ih    = (const float*)d_in[6];
    const float* w_hh    = (const float*)d_in[7];
    const float* b_ih    = (const float*)d_in[8];
    const float* b_hh    = (const float*)d_in[9];
    const float* att_w1  = (const float*)d_in[10];
    const float* att_b1  = (const float*)d_in[11];
    const float* att_w2  = (const float*)d_in[12];
    const float* att_b2  = (const float*)d_in[13];
    float* out = (float*)d_out;
    float* ws  = (float*)d_ws;

    // ws layout (floats)
    float* h      = ws;                      // 4096*256 = 1048576
    float* c      = ws + 1048576;            // 1048576
    float* hid1   = ws + 2097152;            // 1048576 (aliased by preT after use)
    float* preT   = ws + 2097152;            // 2048*256 = 524288 (alias of hid1)
    float* wpk    = ws + 3145728;            // 262144 + 1024 pad row
    float* rowsum = ws + 3408896;            // 1024
    float* e_acc  = ws + 3409920;            // 16*256 = 4096
    float* scores = ws + 3414016;            // 2048
    int*   idxbuf = (int*)(ws + 3416064);    // 16 ints

    hipMemsetAsync(c, 0, (size_t)N_TRAIN * ENC * sizeof(float), stream);
    hipMemsetAsync(e_acc, 0, (size_t)MAX_LEN * ENC * sizeof(float), stream);

    k_rowsum<<<1024, 256, 0, stream>>>(w_ih, rowsum);
    k_pack<<<1024, 256, 0, stream>>>(w_hh, wpk);

    // hidden1 = relu(context @ enc_w1.T + enc_b1)
    dim3 g1(N_TRAIN / 64, N_HID / 64);
    gemm_abT<true><<<g1, 256, 0, stream>>>(context, enc_w1, enc_b1, hid1,
                                           N_TRAIN, N_HID, N_FEAT, N_FEAT, N_FEAT, N_HID);
    // h = phi = hidden1 @ enc_w2.T + enc_b2
    dim3 g2(N_TRAIN / 64, ENC / 64);
    gemm_abT<false><<<g2, 256, 0, stream>>>(hid1, enc_w2, enc_b2, h,
                                            N_TRAIN, ENC, N_HID, N_HID, N_HID, ENC);
    // preT aliases hid1 — zero it only after gemm #2 has consumed hid1
    // (stream-ordered), then accumulate split-K partials atomically.
    hipMemsetAsync(preT, 0, (size_t)ATT_H * N_ANTES * sizeof(float), stream);
    dim3 g3(ATT_H / 64, N_ANTES / 64, KSPLIT);
    gemm_ab_splitk<<<g3, 256, 0, stream>>>(att_w1, S, preT,
                                           ATT_H, N_ANTES, N_TRAIN,
                                           N_TRAIN + ENC, N_ANTES, N_ANTES);

    for (int t = 0; t < MAX_LEN; ++t) {
        k_lstm<<<N_TRAIN / ROWS, 256, 0, stream>>>(h, c, wpk, rowsum, b_ih, b_hh,
                                                   S, idxbuf, t, e_acc + t * 256);
        k_att1<<<N_ANTES / 64, 256, 0, stream>>>(preT, e_acc + t * 256, att_w1,
                                                 att_b1, att_w2, att_b2, scores);
        k_att2<<<1, 256, 0, stream>>>(scores, out + t * N_ANTES, idxbuf + t);
    }
}

// Round 3
// 1185.599 us; speedup vs baseline: 1.2262x; 1.2225x over previous
//
#include <hip/hip_runtime.h>
#include <hip/hip_bf16.h>
#include <math.h>

// Shapes
#define N_TRAIN 4096
#define N_FEAT  64
#define N_HID   256
#define ENC     256
#define N_ANTES 2048
#define ATT_H   256
#define MAX_LEN 16

__device__ __forceinline__ float fsig(float x)  { return 1.f / (1.f + __expf(-x)); }
__device__ __forceinline__ float ftanh(float x) { return 2.f / (1.f + __expf(-2.f * x)) - 1.f; }

// ---------------------------------------------------------------------------
// Generic tiled GEMM: C[m,n] = act(bias[n] + sum_k A[m,k] * B[n,k])
// ---------------------------------------------------------------------------
template <bool RELU>
__global__ __launch_bounds__(256) void gemm_abT(
    const float* __restrict__ A, const float* __restrict__ B,
    const float* __restrict__ bias, float* __restrict__ C,
    int M, int N, int K, int lda, int ldb, int ldc)
{
    __shared__ float As[16][65];
    __shared__ float Bs[16][65];
    const int tid = threadIdx.x;
    const int m0 = blockIdx.x * 64, n0 = blockIdx.y * 64;
    const int tx = tid & 15, ty = tid >> 4;
    const int kl = tid & 15, rl = tid >> 4;
    float acc[4][4] = {};

    for (int k0 = 0; k0 < K; k0 += 16) {
        #pragma unroll
        for (int pp = 0; pp < 4; ++pp) {
            int r = rl + pp * 16;
            As[kl][r] = A[(size_t)(m0 + r) * lda + k0 + kl];
            Bs[kl][r] = B[(size_t)(n0 + r) * ldb + k0 + kl];
        }
        __syncthreads();
        #pragma unroll
        for (int k = 0; k < 16; ++k) {
            float a[4], b[4];
            #pragma unroll
            for (int i = 0; i < 4; ++i) a[i] = As[k][ty * 4 + i];
            #pragma unroll
            for (int i = 0; i < 4; ++i) b[i] = Bs[k][tx * 4 + i];
            #pragma unroll
            for (int i = 0; i < 4; ++i)
                #pragma unroll
                for (int j = 0; j < 4; ++j)
                    acc[i][j] = fmaf(a[i], b[j], acc[i][j]);
        }
        __syncthreads();
    }
    #pragma unroll
    for (int i = 0; i < 4; ++i) {
        int m = m0 + ty * 4 + i;
        #pragma unroll
        for (int j = 0; j < 4; ++j) {
            int n = n0 + tx * 4 + j;
            float v = acc[i][j] + bias[n];
            if (RELU) v = fmaxf(v, 0.f);
            C[(size_t)m * ldc + n] = v;
        }
    }
}

// ---------------------------------------------------------------------------
// Split-K GEMM: C[m,n] += partial over this block's k-chunk (atomicAdd).
// Grid: (M/64, N/64, KSPLIT). Used for preT = Wa @ S.
// ---------------------------------------------------------------------------
#define KSPLIT 16
__global__ __launch_bounds__(256) void gemm_ab_splitk(
    const float* __restrict__ A, const float* __restrict__ B,
    float* __restrict__ C, int M, int N, int K, int lda, int ldb, int ldc)
{
    __shared__ float As[16][65];
    __shared__ float Bs[16][64];
    const int tid = threadIdx.x;
    const int m0 = blockIdx.x * 64, n0 = blockIdx.y * 64;
    const int kchunk = K / KSPLIT;
    const int kbeg = blockIdx.z * kchunk, kend = kbeg + kchunk;
    const int tx = tid & 15, ty = tid >> 4;
    const int kl = tid & 15, rl = tid >> 4;
    const int kb = tid >> 6, nb = tid & 63;
    float acc[4][4] = {};

    for (int k0 = kbeg; k0 < kend; k0 += 16) {
        #pragma unroll
        for (int pp = 0; pp < 4; ++pp) {
            As[kl][rl + pp * 16] = A[(size_t)(m0 + rl + pp * 16) * lda + k0 + kl];
            Bs[kb + pp * 4][nb]  = B[(size_t)(k0 + kb + pp * 4) * ldb + n0 + nb];
        }
        __syncthreads();
        #pragma unroll
        for (int k = 0; k < 16; ++k) {
            float a[4], b[4];
            #pragma unroll
            for (int i = 0; i < 4; ++i) a[i] = As[k][ty * 4 + i];
            #pragma unroll
            for (int i = 0; i < 4; ++i) b[i] = Bs[k][tx * 4 + i];
            #pragma unroll
            for (int i = 0; i < 4; ++i)
                #pragma unroll
                for (int j = 0; j < 4; ++j)
                    acc[i][j] = fmaf(a[i], b[j], acc[i][j]);
        }
        __syncthreads();
    }
    #pragma unroll
    for (int i = 0; i < 4; ++i)
        #pragma unroll
        for (int j = 0; j < 4; ++j)
            atomicAdd(&C[(size_t)(m0 + ty * 4 + i) * ldc + n0 + tx * 4 + j],
                      acc[i][j]);
}

// ---------------------------------------------------------------------------
// rowsum[j] = sum_k w_ih[j, k]
// ---------------------------------------------------------------------------
__global__ __launch_bounds__(256) void k_rowsum(const float* __restrict__ w_ih,
                                                float* __restrict__ rowsum)
{
    __shared__ float red[256];
    const int j = blockIdx.x, tid = threadIdx.x;
    float s = 0.f;
    for (int i = tid; i < N_ANTES; i += 256) s += w_ih[(size_t)j * N_ANTES + i];
    red[tid] = s; __syncthreads();
    for (int off = 128; off > 0; off >>= 1) {
        if (tid < off) red[tid] += red[tid + off];
        __syncthreads();
    }
    if (tid == 0) rowsum[j] = red[0];
}

// ---------------------------------------------------------------------------
// w_pack[k*1024 + jj*4 + g] = w_hh[(g*256+jj)*256 + k]
// ---------------------------------------------------------------------------
__global__ __launch_bounds__(256) void k_pack(const float* __restrict__ w_hh,
                                              float* __restrict__ w_pack)
{
    int gid = blockIdx.x * 256 + threadIdx.x;  // 0..262143
    int row = gid >> 8;
    int k   = gid & 255;
    int g   = row >> 8, jj = row & 255;
    w_pack[(size_t)k * 1024 + jj * 4 + g] = w_hh[gid];
}

// ---------------------------------------------------------------------------
// WbT[k*256 + j] = att_w1[j*(N_TRAIN+ENC) + N_TRAIN + k]
// ---------------------------------------------------------------------------
__global__ __launch_bounds__(256) void k_wbT(const float* __restrict__ att_w1,
                                             float* __restrict__ WbT)
{
    int gid = blockIdx.x * 256 + threadIdx.x;  // 0..65535
    int j = gid >> 8, k = gid & 255;
    WbT[(size_t)k * 256 + j] = att_w1[(size_t)j * (N_TRAIN + ENC) + N_TRAIN + k];
}

// ---------------------------------------------------------------------------
// LSTM step. 16 rows/block, thread tid owns hidden unit jj=tid, all 4 gates.
// x@w_ih.T collapses to a[r]*rowsum[j] (x rank-1). w_pack streamed from L2
// with a 4-deep rotating register prefetch (w_pack padded +4 rows so the
// last prefetches stay in-bounds). h tile transposed in LDS, stride 20.
// ---------------------------------------------------------------------------
#define ROWS 16
#define HSTRIDE 20
__global__ __launch_bounds__(256) void k_lstm(
    float* __restrict__ h, float* __restrict__ c,
    const float* __restrict__ w_pack, const float* __restrict__ rowsum,
    const float* __restrict__ b_ih, const float* __restrict__ b_hh,
    const float* __restrict__ S, const int* __restrict__ idx_buf, int t,
    float* __restrict__ e_accum_t)
{
    __shared__ float h_lds[256 * HSTRIDE];
    __shared__ float a_lds[ROWS];
    const int tid = threadIdx.x;
    const int n0 = blockIdx.x * ROWS;

    if (tid < ROWS) {
        float a = 1.0f;
        if (t > 0) a = S[(size_t)(n0 + tid) * N_ANTES + idx_buf[t - 1]];
        a_lds[tid] = a;
    }
    #pragma unroll
    for (int r = 0; r < ROWS; ++r)
        h_lds[tid * HSTRIDE + r] = h[(size_t)(n0 + r) * 256 + tid];
    __syncthreads();

    float rs[4], bs[4];
    #pragma unroll
    for (int g = 0; g < 4; ++g) {
        int j = g * 256 + tid;
        rs[g] = rowsum[j];
        bs[g] = b_ih[j] + b_hh[j];
    }
    float acc[4][ROWS];
    #pragma unroll
    for (int g = 0; g < 4; ++g)
        #pragma unroll
        for (int r = 0; r < ROWS; ++r)
            acc[g][r] = fmaf(a_lds[r], rs[g], bs[g]);

    const float4* __restrict__ wp4 = (const float4*)w_pack;
    float4 wbuf[4];
    #pragma unroll
    for (int i = 0; i < 4; ++i) wbuf[i] = wp4[(size_t)i * 256 + tid];

    for (int k = 0; k < 256; k += 4) {
        #pragma unroll
        for (int u = 0; u < 4; ++u) {
            float4 w = wbuf[u];
            wbuf[u] = wp4[(size_t)(k + 4 + u) * 256 + tid];  // rows 256..259 = pad
            const float4* hrow = (const float4*)&h_lds[(k + u) * HSTRIDE];
            float4 h0 = hrow[0], h1 = hrow[1], h2 = hrow[2], h3 = hrow[3];
            float hk[ROWS] = {h0.x, h0.y, h0.z, h0.w, h1.x, h1.y, h1.z, h1.w,
                              h2.x, h2.y, h2.z, h2.w, h3.x, h3.y, h3.z, h3.w};
            #pragma unroll
            for (int r = 0; r < ROWS; ++r) {
                acc[0][r] = fmaf(w.x, hk[r], acc[0][r]);
                acc[1][r] = fmaf(w.y, hk[r], acc[1][r]);
                acc[2][r] = fmaf(w.z, hk[r], acc[2][r]);
                acc[3][r] = fmaf(w.w, hk[r], acc[3][r]);
            }
        }
    }

    float esum = 0.f;
    #pragma unroll
    for (int r = 0; r < ROWS; ++r) {
        size_t off = (size_t)(n0 + r) * 256 + tid;
        float cold = c[off];
        float ig = fsig(acc[0][r]);
        float fg = fsig(acc[1][r]);
        float gg = ftanh(acc[2][r]);
        float og = fsig(acc[3][r]);
        float cn = fg * cold + ig * gg;
        float hn = og * ftanh(cn);
        c[off] = cn;
        h[off] = hn;
        esum += hn;
    }
    atomicAdd(&e_accum_t[tid], esum);
}

// ---------------------------------------------------------------------------
// Attention scores, 32 blocks x 256 threads; 4 threads per score column.
// u[j] = att_b1[j] + sum_k e_t[k]*WbT[k,j]  (coalesced; redundant per block)
// scores[p] = att_b2 + sum_j relu(preT[j,p] + u[j]) * att_w2[j]
// ---------------------------------------------------------------------------
__global__ __launch_bounds__(256) void k_att1(
    const float* __restrict__ preT, const float* __restrict__ e_accum_t,
    const float* __restrict__ WbT, const float* __restrict__ att_b1,
    const float* __restrict__ att_w2, const float* __restrict__ att_b2,
    float* __restrict__ scores)
{
    __shared__ float e_lds[256];
    __shared__ float u[256];
    __shared__ float w2s[256];
    __shared__ float red[256];
    const int tid = threadIdx.x;
    e_lds[tid] = e_accum_t[tid] * (1.f / (float)N_TRAIN);
    w2s[tid] = att_w2[tid];
    __syncthreads();

    float uacc = att_b1[tid];
    for (int k = 0; k < 256; ++k)
        uacc = fmaf(e_lds[k], WbT[(size_t)k * 256 + tid], uacc);
    u[tid] = uacc;
    __syncthreads();

    const int pl = tid & 63, jq = tid >> 6;
    const int p = blockIdx.x * 64 + pl;
    float sc = 0.f;
    #pragma unroll 4
    for (int j = jq; j < 256; j += 4) {
        float v = preT[(size_t)j * N_ANTES + p] + u[j];
        sc = fmaf(fmaxf(v, 0.f), w2s[j], sc);
    }
    red[tid] = sc;
    __syncthreads();
    if (tid < 64)
        scores[blockIdx.x * 64 + tid] =
            red[tid] + red[tid + 64] + red[tid + 128] + red[tid + 192] + att_b2[0];
}

// ---------------------------------------------------------------------------
// log-softmax + argmax over 2048 scores (single block)
// ---------------------------------------------------------------------------
__global__ __launch_bounds__(256) void k_att2(
    const float* __restrict__ scores, float* __restrict__ out_t,
    int* __restrict__ idx_t)
{
    __shared__ float smax[256];
    __shared__ int   sidx[256];
    __shared__ float ssum[256];
    const int tid = threadIdx.x;

    float lmax = -INFINITY; int lidx = 0;
    #pragma unroll
    for (int i = 0; i < 8; ++i) {
        int p = tid * 8 + i;
        float s = scores[p];
        if (s > lmax) { lmax = s; lidx = p; }
    }
    smax[tid] = lmax; sidx[tid] = lidx;
    __syncthreads();
    for (int off = 128; off > 0; off >>= 1) {
        if (tid < off) {
            float ov = smax[tid + off]; int oi = sidx[tid + off];
            if (ov > smax[tid] || (ov == smax[tid] && oi < sidx[tid])) {
                smax[tid] = ov; sidx[tid] = oi;
            }
        }
        __syncthreads();
    }
    const float gmax = smax[0];

    float lsum = 0.f;
    #pragma unroll
    for (int i = 0; i < 8; ++i) lsum += __expf(scores[tid * 8 + i] - gmax);
    ssum[tid] = lsum;
    __syncthreads();
    for (int off = 128; off > 0; off >>= 1) {
        if (tid < off) ssum[tid] += ssum[tid + off];
        __syncthreads();
    }
    const float lse = gmax + logf(ssum[0]);

    #pragma unroll
    for (int i = 0; i < 8; ++i) {
        int p = tid * 8 + i;
        out_t[p] = scores[p] - lse;
    }
    if (tid == 0) idx_t[0] = sidx[0];
}

// ---------------------------------------------------------------------------
extern "C" void kernel_launch(void* const* d_in, const int* in_sizes, int n_in,
                              void* d_out, int out_size, void* d_ws, size_t ws_size,
                              hipStream_t stream)
{
    (void)in_sizes; (void)n_in; (void)out_size; (void)ws_size;
    const float* context = (const float*)d_in[0];
    const float* S       = (const float*)d_in[1];
    const float* enc_w1  = (const float*)d_in[2];
    const float* enc_b1  = (const float*)d_in[3];
    const float* enc_w2  = (const float*)d_in[4];
    const float* enc_b2  = (const float*)d_in[5];
    const float* w_ih    = (const float*)d_in[6];
    const float* w_hh    = (const float*)d_in[7];
    const float* b_ih    = (const float*)d_in[8];
    const float* b_hh    = (const float*)d_in[9];
    const float* att_w1  = (const float*)d_in[10];
    const float* att_b1  = (const float*)d_in[11];
    const float* att_w2  = (const float*)d_in[12];
    const float* att_b2  = (const float*)d_in[13];
    float* out = (float*)d_out;
    float* ws  = (float*)d_ws;

    // ws layout (floats)
    float* h      = ws;                      // 1048576
    float* c      = ws + 1048576;            // 1048576
    float* hid1   = ws + 2097152;            // 1048576 (preT aliases)
    float* preT   = ws + 2097152;            // 524288
    float* wpk    = ws + 3145728;            // 262144 + 4096 pad rows
    float* rowsum = ws + 3411968;            // 1024
    float* e_acc  = ws + 3412992;            // 4096
    float* scores = ws + 3417088;            // 2048
    float* WbT    = ws + 3419136;            // 65536
    int*   idxbuf = (int*)(ws + 3484672);    // 16 ints

    hipMemsetAsync(c, 0, (size_t)N_TRAIN * ENC * sizeof(float), stream);
    hipMemsetAsync(e_acc, 0, (size_t)MAX_LEN * ENC * sizeof(float), stream);

    k_rowsum<<<1024, 256, 0, stream>>>(w_ih, rowsum);
    k_pack<<<1024, 256, 0, stream>>>(w_hh, wpk);
    k_wbT<<<256, 256, 0, stream>>>(att_w1, WbT);

    dim3 g1(N_TRAIN / 64, N_HID / 64);
    gemm_abT<true><<<g1, 256, 0, stream>>>(context, enc_w1, enc_b1, hid1,
                                           N_TRAIN, N_HID, N_FEAT, N_FEAT, N_FEAT, N_HID);
    dim3 g2(N_TRAIN / 64, ENC / 64);
    gemm_abT<false><<<g2, 256, 0, stream>>>(hid1, enc_w2, enc_b2, h,
                                            N_TRAIN, ENC, N_HID, N_HID, N_HID, ENC);
    // preT aliases hid1 — zero only after gemm #2 consumed hid1 (stream order)
    hipMemsetAsync(preT, 0, (size_t)ATT_H * N_ANTES * sizeof(float), stream);
    dim3 g3(ATT_H / 64, N_ANTES / 64, KSPLIT);
    gemm_ab_splitk<<<g3, 256, 0, stream>>>(att_w1, S, preT,
                                           ATT_H, N_ANTES, N_TRAIN,
                                           N_TRAIN + ENC, N_ANTES, N_ANTES);

    for (int t = 0; t < MAX_LEN; ++t) {
        k_lstm<<<N_TRAIN / ROWS, 256, 0, stream>>>(h, c, wpk, rowsum, b_ih, b_hh,
                                                   S, idxbuf, t, e_acc + t * 256);
        k_att1<<<N_ANTES / 64, 256, 0, stream>>>(preT, e_acc + t * 256, WbT,
                                                 att_b1, att_w2, att_b2, scores);
        k_att2<<<1, 256, 0, stream>>>(scores, out + t * N_ANTES, idxbuf + t);
    }
}